// Round 1
// baseline (183.419 us; speedup 1.0000x reference)
//
#include <hip/hip_runtime.h>
#include <hip/hip_bf16.h>
#include <math.h>

#define ICH   3
#define OCH   16
#define ID    18
#define IH    34
#define IW    34
#define OD    16
#define OH    32
#define OW    32
#define NB    128
#define PLANE_W  36                 // padded row stride (aligned float4 at w%4==0)
#define PLANE_SZ (PLANE_W * IH)     // 36*34 = 1224 floats per plane
#define DCHUNK   2
#define IN_D     (DCHUNK + 2)       // 4 input d-planes per chunk
#define SPATIAL  (OD * OH * OW)     // 16384 per (b,c)
#define EPSV     1e-5f

__device__ __forceinline__ unsigned short f2bf(float f) {
    unsigned int u = __float_as_uint(f);
    unsigned int r = (u + 0x7fffu + ((u >> 16) & 1u)) >> 16;
    return (unsigned short)r;
}
__device__ __forceinline__ float bf2f(unsigned short h) {
    return __uint_as_float(((unsigned int)h) << 16);
}

// One block per (b, dchunk). 256 threads. Each thread: h = tid>>3, 4 consecutive w.
// Computes all 16 output channels for 2 output d-slices; folds bias + multiplier;
// accumulates per-(b,c) sum/sumsq; stores y as bf16 to workspace.
__global__ __launch_bounds__(256, 2) void conv_stats_kernel(
    const float* __restrict__ x, const float* __restrict__ cw,
    const float* __restrict__ cb, const float* __restrict__ mult,
    unsigned short* __restrict__ y, float* __restrict__ stats)
{
    __shared__ float sx[ICH][IN_D][PLANE_SZ];
    __shared__ float wsum[4][OCH], wsq[4][OCH];

    const int blk = blockIdx.x;
    const int b = blk >> 3;        // 128
    const int d0 = (blk & 7) * DCHUNK;
    const int tid = threadIdx.x;

    // ---- stage input planes: 3 ic x 4 d x 34x34 (padded rows) ----
    for (int idx = tid; idx < ICH * IN_D * IH * IW; idx += 256) {
        int t = idx;
        const int wcol = t % IW; t /= IW;
        const int hrow = t % IH; t /= IH;
        const int dz = t % IN_D; t /= IN_D;
        const int ic = t;
        sx[ic][dz][hrow * PLANE_W + wcol] =
            x[(((size_t)(b * ICH + ic) * ID) + (d0 + dz)) * (IH * IW) + hrow * IW + wcol];
    }
    __syncthreads();

    const int h  = tid >> 3;        // 0..31
    const int wq = (tid & 7) << 2;  // 0,4,...,28

    float ssum[OCH], ssq[OCH];
#pragma unroll
    for (int c = 0; c < OCH; c++) { ssum[c] = 0.0f; ssq[c] = 0.0f; }

    for (int dz = 0; dz < DCHUNK; dz++) {
        float acc[OCH][4];
#pragma unroll
        for (int c = 0; c < OCH; c++) {
            const float bv = cb[c];
            acc[c][0] = bv; acc[c][1] = bv; acc[c][2] = bv; acc[c][3] = bv;
        }

        for (int ic = 0; ic < ICH; ic++) {
            for (int kd = 0; kd < 3; kd++) {
#pragma unroll
                for (int kh = 0; kh < 3; kh++) {
                    const float* row = &sx[ic][dz + kd][(h + kh) * PLANE_W + wq];
                    const float4 v0 = *(const float4*)row;
                    const float2 v1 = *(const float2*)(row + 4);
                    float in[6];
                    in[0] = v0.x; in[1] = v0.y; in[2] = v0.z; in[3] = v0.w;
                    in[4] = v1.x; in[5] = v1.y;
                    const float* wrow = &cw[(size_t)(ic * 3 + kd) * 9 + kh * 3];
#pragma unroll
                    for (int kw = 0; kw < 3; kw++) {
#pragma unroll
                        for (int c = 0; c < OCH; c++) {
                            const float wv = wrow[(size_t)c * (ICH * 27) + kw];
                            acc[c][0] = fmaf(in[kw + 0], wv, acc[c][0]);
                            acc[c][1] = fmaf(in[kw + 1], wv, acc[c][1]);
                            acc[c][2] = fmaf(in[kw + 2], wv, acc[c][2]);
                            acc[c][3] = fmaf(in[kw + 3], wv, acc[c][3]);
                        }
                    }
                }
            }
        }

        // multiplier fold, stats, bf16 store
        const int d = d0 + dz;
#pragma unroll
        for (int c = 0; c < OCH; c++) {
            const float m = mult[c];
            const float o0 = acc[c][0] * m, o1 = acc[c][1] * m;
            const float o2 = acc[c][2] * m, o3 = acc[c][3] * m;
            ssum[c] += (o0 + o1) + (o2 + o3);
            ssq[c]  += (o0 * o0 + o1 * o1) + (o2 * o2 + o3 * o3);
            const size_t yi = ((size_t)(b * OCH + c) * OD + d) * (OH * OW) + h * OW + wq;
            ushort4 pk;
            pk.x = f2bf(o0); pk.y = f2bf(o1); pk.z = f2bf(o2); pk.w = f2bf(o3);
            *(ushort4*)&y[yi] = pk;
        }
    }

    // ---- block reduction of stats, then one atomicAdd per (b,c) pair ----
#pragma unroll
    for (int c = 0; c < OCH; c++) {
        for (int off = 32; off > 0; off >>= 1) {
            ssum[c] += __shfl_down(ssum[c], off);
            ssq[c]  += __shfl_down(ssq[c], off);
        }
    }
    const int wave = tid >> 6, lane = tid & 63;
    if (lane == 0) {
#pragma unroll
        for (int c = 0; c < OCH; c++) { wsum[wave][c] = ssum[c]; wsq[wave][c] = ssq[c]; }
    }
    __syncthreads();
    if (tid < OCH) {
        float s = 0.0f, q = 0.0f;
#pragma unroll
        for (int k = 0; k < 4; k++) { s += wsum[k][tid]; q += wsq[k][tid]; }
        atomicAdd(&stats[(b * OCH + tid) * 2 + 0], s);
        atomicAdd(&stats[(b * OCH + tid) * 2 + 1], q);
    }
}

// Grid: 128 b x 4 quarters. Normalize, clamp, x mult, max over 16 channels.
__global__ __launch_bounds__(256) void norm_max_kernel(
    const unsigned short* __restrict__ y, const float* __restrict__ stats,
    const float* __restrict__ mult, float* __restrict__ out)
{
    const int blk = blockIdx.x;
    const int b = blk >> 2;
    const int q = blk & 3;
    const int tid = threadIdx.x;

    __shared__ float smean[OCH], srstd[OCH], smul[OCH];
    if (tid < OCH) {
        const float s  = stats[(b * OCH + tid) * 2 + 0];
        const float sq = stats[(b * OCH + tid) * 2 + 1];
        const float mean = s * (1.0f / (float)SPATIAL);
        float var = sq * (1.0f / (float)SPATIAL) - mean * mean;
        var = fmaxf(var, 0.0f);
        smean[tid] = mean;
        srstd[tid] = rsqrtf(var + EPSV);
        smul[tid]  = mult[tid];
    }
    __syncthreads();

    const size_t ybase = (size_t)b * OCH * SPATIAL;
#pragma unroll
    for (int k = 0; k < 4; k++) {
        const int s = q * 4096 + k * 1024 + tid * 4;
        float b0 = -INFINITY, b1 = -INFINITY, b2 = -INFINITY, b3 = -INFINITY;
#pragma unroll
        for (int c = 0; c < OCH; c++) {
            const ushort4 v = *(const ushort4*)&y[ybase + (size_t)c * SPATIAL + s];
            const float mn = smean[c], rs = srstd[c], m = smul[c];
            float f0 = (bf2f(v.x) - mn) * rs;
            float f1 = (bf2f(v.y) - mn) * rs;
            float f2 = (bf2f(v.z) - mn) * rs;
            float f3 = (bf2f(v.w) - mn) * rs;
            f0 = fminf(fmaxf(f0, -1.0f), 1.0f) * m;
            f1 = fminf(fmaxf(f1, -1.0f), 1.0f) * m;
            f2 = fminf(fmaxf(f2, -1.0f), 1.0f) * m;
            f3 = fminf(fmaxf(f3, -1.0f), 1.0f) * m;
            b0 = fmaxf(b0, f0); b1 = fmaxf(b1, f1);
            b2 = fmaxf(b2, f2); b3 = fmaxf(b3, f3);
        }
        float4 o; o.x = b0; o.y = b1; o.z = b2; o.w = b3;
        *(float4*)&out[(size_t)b * SPATIAL + s] = o;
    }
}

extern "C" void kernel_launch(void* const* d_in, const int* in_sizes, int n_in,
                              void* d_out, int out_size, void* d_ws, size_t ws_size,
                              hipStream_t stream) {
    const float* x    = (const float*)d_in[0];
    const float* cw   = (const float*)d_in[1];
    const float* cb   = (const float*)d_in[2];
    const float* mult = (const float*)d_in[3];
    float* out = (float*)d_out;

    // workspace layout: y (bf16, 33,554,432 elems = 64 MB) | stats (2048*2 f32 = 16 KB)
    unsigned short* y = (unsigned short*)d_ws;
    float* stats = (float*)((char*)d_ws + (size_t)NB * OCH * SPATIAL * sizeof(unsigned short));

    hipMemsetAsync(stats, 0, (size_t)NB * OCH * 2 * sizeof(float), stream);
    conv_stats_kernel<<<NB * (OD / DCHUNK), 256, 0, stream>>>(x, cw, cb, mult, y, stats);
    norm_max_kernel<<<NB * 4, 256, 0, stream>>>(y, stats, mult, out);
}

// Round 2
// 183.309 us; speedup vs baseline: 1.0006x; 1.0006x over previous
//
#include <hip/hip_runtime.h>
#include <hip/hip_bf16.h>
#include <math.h>

#define ICH   3
#define OCH   16
#define ID    18
#define IH    34
#define IW    34
#define OD    16
#define OH    32
#define OW    32
#define NB    128
#define PLANE_W  36                 // padded row stride (16B-aligned float4 at w%4==0)
#define HH       16                 // output rows per block (h-half)
#define SROWS    (HH + 2)           // 18 staged input rows
#define PLANE_SZ (PLANE_W * SROWS)  // 648 floats per staged plane
#define NPLANES  (ICH * 4)          // 3 ic x 4 d-slices = 12 planes
#define SPATIAL  (OD * OH * OW)     // 16384 per (b,c)
#define EPSV     1e-5f

__device__ __forceinline__ unsigned short f2bf(float f) {
    unsigned int u = __float_as_uint(f);
    unsigned int r = (u + 0x7fffu + ((u >> 16) & 1u)) >> 16;
    return (unsigned short)r;
}
__device__ __forceinline__ float bf2f(unsigned short h) {
    return __uint_as_float(((unsigned int)h) << 16);
}

// Grid: 128 b x 8 dchunk x 2 hhalf = 2048 blocks, 256 threads.
// Waves 0-1: dz=0, waves 2-3: dz=1. Thread: h=(tid>>3)&15, 4 consecutive w, all 16 oc.
// LDS 31.1 KB -> 5 blocks/CU (20 waves/CU).
__global__ __launch_bounds__(256, 5) void conv_stats_kernel(
    const float* __restrict__ x, const float* __restrict__ cw,
    const float* __restrict__ cb, const float* __restrict__ mult,
    unsigned short* __restrict__ y, float* __restrict__ stats)
{
    __shared__ float sx[NPLANES][PLANE_SZ];   // 12 x 648 x 4B = 31104 B
    __shared__ float wsum[4][OCH], wsq[4][OCH];

    const int blk = blockIdx.x;
    const int b  = blk >> 4;
    const int r  = blk & 15;
    const int d0 = (r >> 1) * 2;
    const int h0 = (r & 1) * HH;
    const int tid = threadIdx.x;

    // ---- stage 12 planes x 18 rows x 34 cols as float2 (both gmem+LDS 8B-aligned) ----
    // i over 12*18*17 = 3672 float2 slots
    for (int i = tid; i < NPLANES * SROWS * 17; i += 256) {
        const int row   = i / 17;           // magic-mul
        const int col2  = (i - row * 17) * 2;
        const int plane = row / SROWS;      // magic-mul
        const int prow  = row - plane * SROWS;
        const int ic = plane >> 2, dz = plane & 3;
        const float2 v = *(const float2*)&x[
            ((size_t)(b * ICH + ic) * ID + (d0 + dz)) * (IH * IW)
            + (size_t)(h0 + prow) * IW + col2];
        *(float2*)&sx[plane][prow * PLANE_W + col2] = v;
    }
    __syncthreads();

    const int dz = tid >> 7;         // wave-uniform: waves 0-1 -> 0, waves 2-3 -> 1
    const int h  = (tid >> 3) & 15;  // local output row 0..15
    const int wq = (tid & 7) << 2;   // 0,4,...,28

    float acc[OCH][4];
#pragma unroll
    for (int c = 0; c < OCH; c++) {
        const float bv = cb[c];
        acc[c][0] = bv; acc[c][1] = bv; acc[c][2] = bv; acc[c][3] = bv;
    }

    for (int ic = 0; ic < ICH; ic++) {
#pragma unroll
        for (int kd = 0; kd < 3; kd++) {
            const float* pl = &sx[ic * 4 + dz + kd][0];
#pragma unroll
            for (int kh = 0; kh < 3; kh++) {
                const float* row = pl + (h + kh) * PLANE_W + wq;
                const float4 v0 = *(const float4*)row;
                const float2 v1 = *(const float2*)(row + 4);
                float in[6];
                in[0] = v0.x; in[1] = v0.y; in[2] = v0.z; in[3] = v0.w;
                in[4] = v1.x; in[5] = v1.y;
                const float* wrow = &cw[(ic * 3 + kd) * 9 + kh * 3];
#pragma unroll
                for (int kw = 0; kw < 3; kw++) {
#pragma unroll
                    for (int c = 0; c < OCH; c++) {
                        const float wv = wrow[c * (ICH * 27) + kw];
                        acc[c][0] = fmaf(in[kw + 0], wv, acc[c][0]);
                        acc[c][1] = fmaf(in[kw + 1], wv, acc[c][1]);
                        acc[c][2] = fmaf(in[kw + 2], wv, acc[c][2]);
                        acc[c][3] = fmaf(in[kw + 3], wv, acc[c][3]);
                    }
                }
            }
        }
    }

    // ---- multiplier fold, stats, bf16 store ----
    float ssum[OCH], ssq[OCH];
    const int d = d0 + dz;
#pragma unroll
    for (int c = 0; c < OCH; c++) {
        const float m = mult[c];
        const float o0 = acc[c][0] * m, o1 = acc[c][1] * m;
        const float o2 = acc[c][2] * m, o3 = acc[c][3] * m;
        ssum[c] = (o0 + o1) + (o2 + o3);
        ssq[c]  = (o0 * o0 + o1 * o1) + (o2 * o2 + o3 * o3);
        const size_t yi = ((size_t)(b * OCH + c) * OD + d) * (OH * OW)
                          + (size_t)(h0 + h) * OW + wq;
        ushort4 pk;
        pk.x = f2bf(o0); pk.y = f2bf(o1); pk.z = f2bf(o2); pk.w = f2bf(o3);
        *(ushort4*)&y[yi] = pk;
    }

    // ---- block reduction of stats, one atomicAdd per (b,c) ----
#pragma unroll
    for (int c = 0; c < OCH; c++) {
        for (int off = 32; off > 0; off >>= 1) {
            ssum[c] += __shfl_down(ssum[c], off);
            ssq[c]  += __shfl_down(ssq[c], off);
        }
    }
    const int wave = tid >> 6, lane = tid & 63;
    if (lane == 0) {
#pragma unroll
        for (int c = 0; c < OCH; c++) { wsum[wave][c] = ssum[c]; wsq[wave][c] = ssq[c]; }
    }
    __syncthreads();
    if (tid < OCH) {
        float s = 0.0f, q = 0.0f;
#pragma unroll
        for (int k = 0; k < 4; k++) { s += wsum[k][tid]; q += wsq[k][tid]; }
        atomicAdd(&stats[(b * OCH + tid) * 2 + 0], s);
        atomicAdd(&stats[(b * OCH + tid) * 2 + 1], q);
    }
}

// Grid: 128 b x 16 segments = 2048 blocks. Each thread: 4 consecutive positions, 16 ch.
__global__ __launch_bounds__(256) void norm_max_kernel(
    const unsigned short* __restrict__ y, const float* __restrict__ stats,
    const float* __restrict__ mult, float* __restrict__ out)
{
    const int blk = blockIdx.x;
    const int b   = blk >> 4;
    const int seg = blk & 15;
    const int tid = threadIdx.x;

    __shared__ float smean[OCH], srstd[OCH], smul[OCH];
    if (tid < OCH) {
        const float s  = stats[(b * OCH + tid) * 2 + 0];
        const float sq = stats[(b * OCH + tid) * 2 + 1];
        const float mean = s * (1.0f / (float)SPATIAL);
        float var = sq * (1.0f / (float)SPATIAL) - mean * mean;
        var = fmaxf(var, 0.0f);
        smean[tid] = mean;
        srstd[tid] = rsqrtf(var + EPSV);
        smul[tid]  = mult[tid];
    }
    __syncthreads();

    const size_t ybase = (size_t)b * OCH * SPATIAL;
    const int s = seg * 1024 + tid * 4;
    float b0 = -INFINITY, b1 = -INFINITY, b2 = -INFINITY, b3 = -INFINITY;
#pragma unroll
    for (int c = 0; c < OCH; c++) {
        const ushort4 v = *(const ushort4*)&y[ybase + (size_t)c * SPATIAL + s];
        const float mn = smean[c], rs = srstd[c], m = smul[c];
        float f0 = (bf2f(v.x) - mn) * rs;
        float f1 = (bf2f(v.y) - mn) * rs;
        float f2 = (bf2f(v.z) - mn) * rs;
        float f3 = (bf2f(v.w) - mn) * rs;
        f0 = fminf(fmaxf(f0, -1.0f), 1.0f) * m;
        f1 = fminf(fmaxf(f1, -1.0f), 1.0f) * m;
        f2 = fminf(fmaxf(f2, -1.0f), 1.0f) * m;
        f3 = fminf(fmaxf(f3, -1.0f), 1.0f) * m;
        b0 = fmaxf(b0, f0); b1 = fmaxf(b1, f1);
        b2 = fmaxf(b2, f2); b3 = fmaxf(b3, f3);
    }
    float4 o; o.x = b0; o.y = b1; o.z = b2; o.w = b3;
    *(float4*)&out[(size_t)b * SPATIAL + s] = o;
}

extern "C" void kernel_launch(void* const* d_in, const int* in_sizes, int n_in,
                              void* d_out, int out_size, void* d_ws, size_t ws_size,
                              hipStream_t stream) {
    const float* x    = (const float*)d_in[0];
    const float* cw   = (const float*)d_in[1];
    const float* cb   = (const float*)d_in[2];
    const float* mult = (const float*)d_in[3];
    float* out = (float*)d_out;

    // workspace: y (bf16, 33,554,432 elems = 64 MB) | stats (2048*2 f32)
    unsigned short* y = (unsigned short*)d_ws;
    float* stats = (float*)((char*)d_ws + (size_t)NB * OCH * SPATIAL * sizeof(unsigned short));

    hipMemsetAsync(stats, 0, (size_t)NB * OCH * 2 * sizeof(float), stream);
    conv_stats_kernel<<<NB * 16, 256, 0, stream>>>(x, cw, cb, mult, y, stats);
    norm_max_kernel<<<NB * 16, 256, 0, stream>>>(y, stats, mult, out);
}